// Round 17
// baseline (83.373 us; speedup 1.0000x reference)
//
#include <hip/hip_runtime.h>
#include <hip/hip_bf16.h>

// MSA: B=4, S=2048, D=256, H=8, DH=32
// ATTRIBUTION PROBE ROUND: kernels identical to r16; attn launched TWICE
// (deterministic + idempotent) so dur_us(r17) - dur_us(r16) = attn cost.
//
// proj: LDS-staged GEMM + V output transposed through LDS (16B-contiguous
// Vt stores). attn: split-K (r14): 4 waves x 512-key quarters, wave-private
// LDS double buffers, no in-loop barriers; 32x32x16 MFMA; sigma-permuted K
// rows so QK acc regs ARE the PV B-frags; no-max softmax (exact split-K).

#define NB 4
#define NS 2048
#define ND 256
#define NH 8
#define NDH 32
#define KW 512           // keys per wave (split-K quarter)
#define NTW (KW / 32)    // 16 sub-tiles of 32 keys per wave

typedef __attribute__((ext_vector_type(8))) short short8;
typedef __attribute__((ext_vector_type(4))) float float4v;
typedef __attribute__((ext_vector_type(16))) float float16v;

static __device__ __forceinline__ unsigned short f2bf(float f) {
    union { float f; unsigned int u; } v; v.f = f;
    unsigned int r = (v.u + 0x7FFFu + ((v.u >> 16) & 1u)) >> 16;
    return (unsigned short)r;
}

static __device__ __forceinline__ unsigned int pk2bf(float lo, float hi) {
    __hip_bfloat162 h = __float22bfloat162_rn(float2{lo, hi});  // x=lo -> low 16 bits
    union { __hip_bfloat162 h; unsigned int u; } c; c.h = h;
    return c.u;
}

#if defined(__has_builtin)
#if __has_builtin(__builtin_amdgcn_exp2f)
#define EXP2F(x) __builtin_amdgcn_exp2f(x)
#endif
#endif
#ifndef EXP2F
#define EXP2F(x) exp2f(x)
#endif

// ---------------- fused prep: seq f32->bf16 (blocks 0..2047), W transpose (2048..2815) ----------------
__global__ __launch_bounds__(256) void prep(const float* __restrict__ seq,
                                            unsigned short* __restrict__ seqb,
                                            const float* __restrict__ Wq,
                                            const float* __restrict__ Wk,
                                            const float* __restrict__ Wv,
                                            unsigned short* __restrict__ Wt) {
    int bx = (int)blockIdx.x;
    if (bx < 2048) {
        int i = (bx * 256 + (int)threadIdx.x) * 4;  // 2M elems / 4
        float4 v = *(const float4*)(seq + i);
        ushort4 o;
        o.x = f2bf(v.x); o.y = f2bf(v.y); o.z = f2bf(v.z); o.w = f2bf(v.w);
        *(ushort4*)(seqb + i) = o;
    } else {
        int idx = (bx - 2048) * 256 + (int)threadIdx.x;  // 768*256
        int c = idx >> 8, d = idx & 255;
        int mat = c >> 8;
        int cm = c & 255;
        int h = cm >> 5, e = cm & 31;
        const float* W = (mat == 0) ? Wq : (mat == 1) ? Wk : Wv;
        Wt[c * 256 + d] = f2bf(W[(h * 256 + d) * 32 + e]);
    }
}

// ---------------- projection GEMM: M=8192, N=768, K=256, LDS-staged ----------------
__global__ __launch_bounds__(256, 2) void proj(const unsigned short* __restrict__ seqb,
                                               const unsigned short* __restrict__ Wt,
                                               const float* __restrict__ bq,
                                               const float* __restrict__ bk,
                                               const float* __restrict__ bv,
                                               unsigned short* __restrict__ Q,
                                               unsigned short* __restrict__ K,
                                               unsigned short* __restrict__ Vt) {
    __shared__ __align__(16) unsigned short plds[32768];  // A [0,16384), B [16384,32768)

    int m0 = blockIdx.x * 64;        // 128 m-blocks
    int c0 = blockIdx.y * 64;        // 12 c-blocks (64-col tiles never cross a matrix boundary)
    int tid = (int)threadIdx.x;
    int wave = tid >> 6, lane = tid & 63;
    int g = lane >> 4, r4 = lane & 15;

#pragma unroll
    for (int j = 0; j < 16; ++j) {
        int s = tid + 256 * j;
        int local = s & 2047;
        int row = local >> 5;
        int col16 = (local & 31) ^ (row & 7);
        const unsigned short* src = (s < 2048)
            ? (seqb + (size_t)(m0 + row) * 256 + col16 * 8)
            : (Wt + (size_t)(c0 + row) * 256 + col16 * 8);
        __builtin_amdgcn_global_load_lds(
            (const __attribute__((address_space(1))) unsigned int*)src,
            (__attribute__((address_space(3))) unsigned int*)(&plds[s * 8]), 16, 0, 0);
    }
    __syncthreads();  // drains vmcnt(0): both tiles resident

    const unsigned short* ldsA = plds;
    const unsigned short* ldsB = plds + 16384;
    int rowA = wave * 16 + r4;
    int xA = r4 & 7;

    float4v acc[4];
#pragma unroll
    for (int ct = 0; ct < 4; ++ct) acc[ct] = (float4v){0.f, 0.f, 0.f, 0.f};

#pragma unroll
    for (int i = 0; i < 8; ++i) {
        int cp = ((4 * i + g) ^ xA) * 8;
        short8 a = *(const short8*)(ldsA + rowA * 256 + cp);
#pragma unroll
        for (int ct = 0; ct < 4; ++ct) {
            short8 b = *(const short8*)(ldsB + (ct * 16 + r4) * 256 + cp);
            acc[ct] = __builtin_amdgcn_mfma_f32_16x16x32_bf16(a, b, acc[ct], 0, 0, 0);
        }
    }

    const float SC = 0.17677669529663687f * 1.4426950408889634f;  // 1/sqrt(32)*log2(e)
    if (c0 < 512) {
        // ---- Q/K path: direct stores ----
#pragma unroll
        for (int ct = 0; ct < 4; ++ct) {
            int c = c0 + ct * 16 + r4;
            int mat = c >> 8;
            int cm = c & 255;
            int h = cm >> 5, e = cm & 31;
            float bias = ((mat == 0) ? bq : bk)[cm];
#pragma unroll
            for (int r = 0; r < 4; ++r) {
                int m = m0 + wave * 16 + 4 * g + r;
                int b = m >> 11, s = m & 2047;
                float val = acc[ct][r] + bias;
                if (mat == 0) Q[((b * NH + h) * NS + s) * NDH + e] = f2bf(val * SC);
                else          K[((b * NH + h) * NS + s) * NDH + e] = f2bf(val);
            }
        }
    } else {
        // ---- V path: LDS transpose, then 16B-contiguous stores ----
        int cmb = c0 & 255;                 // = c0 - 512
        unsigned short* T = plds;           // reuse (72-short padded rows)
        __syncthreads();                    // all MFMA reads of plds done
#pragma unroll
        for (int ct = 0; ct < 4; ++ct) {
            int j = ct * 16 + r4;           // local col (h,e index)
            float bias = bv[cmb + j];
#pragma unroll
            for (int r = 0; r < 4; ++r) {
                int i = wave * 16 + 4 * g + r;  // local m
                T[j * 72 + i] = f2bf(acc[ct][r] + bias);
            }
        }
        __syncthreads();
        int b = m0 >> 11, s0 = m0 & 2047;
#pragma unroll
        for (int kk = 0; kk < 2; ++kk) {
            int cid = tid + kk * 256;       // 512 chunks of 16B
            int j = cid >> 3, ch = cid & 7;
            int cm = cmb + j;
            int h = cm >> 5, e = cm & 31;
            short8 v = *(const short8*)(T + j * 72 + ch * 8);
            *(short8*)(Vt + ((size_t)(b * NH + h) * NDH + e) * NS + s0 + ch * 8) = v;
        }
    }
}

// ---------------- flash attention: split-K, wave-private pipelines (r14) ----------------
__global__ __launch_bounds__(256, 4) void attn_kernel(const unsigned short* __restrict__ Q,
                                                      const unsigned short* __restrict__ K,
                                                      const unsigned short* __restrict__ Vt,
                                                      float* __restrict__ out) {
    __shared__ __align__(16) char smem[37888];  // stage 32KB (union) | part 36864B | pll 1KB

    int bx = (int)blockIdx.x;
    int wid = (bx & 7) * 128 + (bx >> 3);  // XCD swizzle (1024 % 8 == 0)
    int bh = wid >> 5;
    int qt = wid & 31;
    int tid = (int)threadIdx.x;
    int wave = tid >> 6, lane = tid & 63;
    int r31 = lane & 31, hi2 = lane >> 5;
    int q0 = qt * 64;
    int kv0 = wave * KW;

    const unsigned short* Qb = Q + (size_t)bh * NS * NDH;
    const unsigned short* Kb = K + (size_t)bh * NS * NDH;
    const unsigned short* Vb = Vt + (size_t)bh * NDH * NS;

    auto mkK = [&](int slot) -> const unsigned short* {
        int row = slot >> 2;
        int srcC = (slot & 3) ^ ((row >> 1) & 3);
        int key = (row & ~12) | ((row & 4) << 1) | ((row & 8) >> 1);  // swap bits 2,3
        return Kb + (size_t)(kv0 + key) * NDH + srcC * 8;
    };
    auto mkV = [&](int sp) -> const unsigned short* {
        int row = sp >> 2;
        int srcC = (sp & 3) ^ ((row >> 1) & 3);
        return Vb + (size_t)row * NS + kv0 + srcC * 8;
    };
    const unsigned short* sp0 = mkK(lane);
    const unsigned short* sp1 = mkK(64 + lane);
    const unsigned short* sp2 = mkV(lane);
    const unsigned short* sp3 = mkV(64 + lane);

    char* bufA = smem + wave * 8192;
    char* bufB = bufA + 4096;

#define GLD(srcp, dstp)                                                        \
    __builtin_amdgcn_global_load_lds(                                          \
        (const __attribute__((address_space(1))) unsigned int*)(srcp),         \
        (__attribute__((address_space(3))) unsigned int*)(dstp), 16, 0, 0)

#define STAGE(bufp, t)                                                         \
    do {                                                                       \
        GLD(sp0 + (t) * 1024, (bufp) + lane * 16);                             \
        GLD(sp1 + (t) * 1024, (bufp) + 1024 + lane * 16);                      \
        GLD(sp2 + (t) * 32,   (bufp) + 2048 + lane * 16);                      \
        GLD(sp3 + (t) * 32,   (bufp) + 3072 + lane * 16);                      \
    } while (0)

    int rx = (r31 >> 1) & 3;
    int kOffA = r31 * 64 + ((hi2 ^ rx) << 4);
    int kOffB = r31 * 64 + (((2 + hi2) ^ rx) << 4);
    int vOffA = 2048 + r31 * 64 + ((hi2 ^ rx) << 4);
    int vOffB = 2048 + r31 * 64 + (((2 + hi2) ^ rx) << 4);

    const unsigned short* qrow0 = Qb + (q0 + r31) * NDH;
    const unsigned short* qrow1 = Qb + (q0 + 32 + r31) * NDH;
    short8 qa0 = *(const short8*)(qrow0 + 8 * hi2);
    short8 qb0 = *(const short8*)(qrow0 + 16 + 8 * hi2);
    short8 qa1 = *(const short8*)(qrow1 + 8 * hi2);
    short8 qb1 = *(const short8*)(qrow1 + 16 + 8 * hi2);
    asm volatile("s_waitcnt vmcnt(0)" ::: "memory");
    __builtin_amdgcn_sched_barrier(0);

    float16v acc0 = {0.f}, acc1 = {0.f};
    const float16v zero16 = {0.f};
    float l0 = 0.f, l1 = 0.f;

    auto process = [&](const char* buf) {
        short8 kfA = *(const short8*)(buf + kOffA);
        short8 kfB = *(const short8*)(buf + kOffB);
        short8 vfA = *(const short8*)(buf + vOffA);
        short8 vfB = *(const short8*)(buf + vOffB);
        {
            float16v s = __builtin_amdgcn_mfma_f32_32x32x16_bf16(kfA, qa0, zero16, 0, 0, 0);
            s = __builtin_amdgcn_mfma_f32_32x32x16_bf16(kfB, qb0, s, 0, 0, 0);
            float p[16];
#pragma unroll
            for (int r = 0; r < 16; ++r) p[r] = EXP2F(s[r]);
#pragma unroll
            for (int r = 0; r < 16; ++r) l0 += p[r];
            union { short8 v; unsigned int u[4]; } pb1, pb2;
#pragma unroll
            for (int w = 0; w < 4; ++w) {
                pb1.u[w] = pk2bf(p[2 * w], p[2 * w + 1]);
                pb2.u[w] = pk2bf(p[8 + 2 * w], p[9 + 2 * w]);
            }
            acc0 = __builtin_amdgcn_mfma_f32_32x32x16_bf16(vfA, pb1.v, acc0, 0, 0, 0);
            acc0 = __builtin_amdgcn_mfma_f32_32x32x16_bf16(vfB, pb2.v, acc0, 0, 0, 0);
        }
        {
            float16v s = __builtin_amdgcn_mfma_f32_32x32x16_bf16(kfA, qa1, zero16, 0, 0, 0);
            s = __builtin_amdgcn_mfma_f32_32x32x16_bf16(kfB, qb1, s, 0, 0, 0);
            float p[16];
#pragma unroll
            for (int r = 0; r < 16; ++r) p[r] = EXP2F(s[r]);
#pragma unroll
            for (int r = 0; r < 16; ++r) l1 += p[r];
            union { short8 v; unsigned int u[4]; } pb1, pb2;
#pragma unroll
            for (int w = 0; w < 4; ++w) {
                pb1.u[w] = pk2bf(p[2 * w], p[2 * w + 1]);
                pb2.u[w] = pk2bf(p[8 + 2 * w], p[9 + 2 * w]);
            }
            acc1 = __builtin_amdgcn_mfma_f32_32x32x16_bf16(vfA, pb1.v, acc1, 0, 0, 0);
            acc1 = __builtin_amdgcn_mfma_f32_32x32x16_bf16(vfB, pb2.v, acc1, 0, 0, 0);
        }
    };

    STAGE(bufA, 0);
    for (int t = 0; t < NTW; t += 2) {
        STAGE(bufB, t + 1);
        asm volatile("s_waitcnt vmcnt(4)" ::: "memory");
        __builtin_amdgcn_sched_barrier(0);
        __builtin_amdgcn_s_setprio(1);
        process(bufA);
        __builtin_amdgcn_s_setprio(0);

        if (t + 2 < NTW) {
            STAGE(bufA, t + 2);
            asm volatile("s_waitcnt vmcnt(4)" ::: "memory");
        } else {
            asm volatile("s_waitcnt vmcnt(0)" ::: "memory");
        }
        __builtin_amdgcn_sched_barrier(0);
        __builtin_amdgcn_s_setprio(1);
        process(bufB);
        __builtin_amdgcn_s_setprio(0);
    }

    // ---- split-K combine via LDS (exact: no-max softmax partials are additive) ----
    l0 += __shfl_xor(l0, 32);
    l1 += __shfl_xor(l1, 32);

    __syncthreads();
    float* part = (float*)smem;                 // [4][64][36] f32 (padded rows)
    float* pll = (float*)(smem + 36864);        // [4][64] f32
#pragma unroll
    for (int j = 0; j < 2; ++j) {
        int qlocal = 32 * j + r31;
        float* prow = part + (wave * 64 + qlocal) * 36 + 4 * hi2;
        const float16v& A = j ? acc1 : acc0;
#pragma unroll
        for (int i = 0; i < 4; ++i) {
            float4 v4 = {A[4 * i], A[4 * i + 1], A[4 * i + 2], A[4 * i + 3]};
            *(float4*)(prow + 8 * i) = v4;
        }
    }
    if (lane < 32) {
        pll[wave * 64 + r31] = l0;
        pll[wave * 64 + 32 + r31] = l1;
    }
    __syncthreads();

    {
        int q = tid >> 2, ch = tid & 3;
        float lsum = pll[q] + pll[64 + q] + pll[128 + q] + pll[192 + q];
        float inv = 1.0f / lsum;
        float4 s0 = {0.f, 0.f, 0.f, 0.f}, s1 = {0.f, 0.f, 0.f, 0.f};
#pragma unroll
        for (int w = 0; w < 4; ++w) {
            const float* prow = part + (w * 64 + q) * 36 + ch * 8;
            float4 a = *(const float4*)(prow);
            float4 b = *(const float4*)(prow + 4);
            s0.x += a.x; s0.y += a.y; s0.z += a.z; s0.w += a.w;
            s1.x += b.x; s1.y += b.y; s1.z += b.z; s1.w += b.w;
        }
        s0.x *= inv; s0.y *= inv; s0.z *= inv; s0.w *= inv;
        s1.x *= inv; s1.y *= inv; s1.z *= inv; s1.w *= inv;
        int b = bh >> 3, h = bh & 7;
        int srow = q0 + q;
        float* op = out + (size_t)(b * NS + srow) * ND + h * NDH + ch * 8;
        *(float4*)(op) = s0;
        *(float4*)(op + 4) = s1;
    }
#undef STAGE
#undef GLD
}

extern "C" void kernel_launch(void* const* d_in, const int* in_sizes, int n_in,
                              void* d_out, int out_size, void* d_ws, size_t ws_size,
                              hipStream_t stream) {
    const float* seq = (const float*)d_in[0];
    const float* Wq = (const float*)d_in[1];
    const float* Wk = (const float*)d_in[2];
    const float* Wv = (const float*)d_in[3];
    const float* bq = (const float*)d_in[4];
    const float* bk = (const float*)d_in[5];
    const float* bv = (const float*)d_in[6];
    float* out = (float*)d_out;

    // workspace layout (bf16 elements): seqb 2M | Wt 196608 | Q 2M | K 2M | Vt 2M  (~17.2 MB)
    unsigned short* seqb = (unsigned short*)d_ws;
    unsigned short* Wt = seqb + 2097152;
    unsigned short* Qw = Wt + 196608;
    unsigned short* Kw = Qw + 2097152;
    unsigned short* Vtw = Kw + 2097152;

    hipLaunchKernelGGL(prep, dim3(2816), dim3(256), 0, stream, seq, seqb, Wq, Wk, Wv, Wt);
    hipLaunchKernelGGL(proj, dim3(128, 12), dim3(256), 0, stream, seqb, Wt, bq, bk, bv, Qw, Kw, Vtw);
    // ATTRIBUTION PROBE: attn launched twice (idempotent). dur_us delta vs
    // r16 (53.8) = attn's marginal cost.
    hipLaunchKernelGGL(attn_kernel, dim3(1024), dim3(256), 0, stream, Qw, Kw, Vtw, out);
    hipLaunchKernelGGL(attn_kernel, dim3(1024), dim3(256), 0, stream, Qw, Kw, Vtw, out);
}

// Round 18
// 67.575 us; speedup vs baseline: 1.2338x; 1.2338x over previous
//
#include <hip/hip_runtime.h>
#include <hip/hip_bf16.h>

// MSA: B=4, S=2048, D=256, H=8, DH=32
// ATTRIBUTION PROBE #2: kernels identical to r16; prep and proj launched
// TWICE each (pure functions of inputs -> idempotent). attn once.
// dur(r18) - 53.8 = prep+proj cost; 24.2 - that = graph-gap overhead.
//
// proj: LDS-staged GEMM + V output transposed through LDS (16B-contiguous
// Vt stores). attn: split-K: 4 waves x 512-key quarters, wave-private LDS
// double buffers, no in-loop barriers; 32x32x16 MFMA; sigma-permuted K rows
// so QK acc regs ARE the PV B-frags; no-max softmax (exact split-K).

#define NB 4
#define NS 2048
#define ND 256
#define NH 8
#define NDH 32
#define KW 512           // keys per wave (split-K quarter)
#define NTW (KW / 32)    // 16 sub-tiles of 32 keys per wave

typedef __attribute__((ext_vector_type(8))) short short8;
typedef __attribute__((ext_vector_type(4))) float float4v;
typedef __attribute__((ext_vector_type(16))) float float16v;

static __device__ __forceinline__ unsigned short f2bf(float f) {
    union { float f; unsigned int u; } v; v.f = f;
    unsigned int r = (v.u + 0x7FFFu + ((v.u >> 16) & 1u)) >> 16;
    return (unsigned short)r;
}

static __device__ __forceinline__ unsigned int pk2bf(float lo, float hi) {
    __hip_bfloat162 h = __float22bfloat162_rn(float2{lo, hi});  // x=lo -> low 16 bits
    union { __hip_bfloat162 h; unsigned int u; } c; c.h = h;
    return c.u;
}

#if defined(__has_builtin)
#if __has_builtin(__builtin_amdgcn_exp2f)
#define EXP2F(x) __builtin_amdgcn_exp2f(x)
#endif
#endif
#ifndef EXP2F
#define EXP2F(x) exp2f(x)
#endif

// ---------------- fused prep: seq f32->bf16 (blocks 0..2047), W transpose (2048..2815) ----------------
__global__ __launch_bounds__(256) void prep(const float* __restrict__ seq,
                                            unsigned short* __restrict__ seqb,
                                            const float* __restrict__ Wq,
                                            const float* __restrict__ Wk,
                                            const float* __restrict__ Wv,
                                            unsigned short* __restrict__ Wt) {
    int bx = (int)blockIdx.x;
    if (bx < 2048) {
        int i = (bx * 256 + (int)threadIdx.x) * 4;  // 2M elems / 4
        float4 v = *(const float4*)(seq + i);
        ushort4 o;
        o.x = f2bf(v.x); o.y = f2bf(v.y); o.z = f2bf(v.z); o.w = f2bf(v.w);
        *(ushort4*)(seqb + i) = o;
    } else {
        int idx = (bx - 2048) * 256 + (int)threadIdx.x;  // 768*256
        int c = idx >> 8, d = idx & 255;
        int mat = c >> 8;
        int cm = c & 255;
        int h = cm >> 5, e = cm & 31;
        const float* W = (mat == 0) ? Wq : (mat == 1) ? Wk : Wv;
        Wt[c * 256 + d] = f2bf(W[(h * 256 + d) * 32 + e]);
    }
}

// ---------------- projection GEMM: M=8192, N=768, K=256, LDS-staged ----------------
__global__ __launch_bounds__(256, 2) void proj(const unsigned short* __restrict__ seqb,
                                               const unsigned short* __restrict__ Wt,
                                               const float* __restrict__ bq,
                                               const float* __restrict__ bk,
                                               const float* __restrict__ bv,
                                               unsigned short* __restrict__ Q,
                                               unsigned short* __restrict__ K,
                                               unsigned short* __restrict__ Vt) {
    __shared__ __align__(16) unsigned short plds[32768];  // A [0,16384), B [16384,32768)

    int m0 = blockIdx.x * 64;        // 128 m-blocks
    int c0 = blockIdx.y * 64;        // 12 c-blocks (64-col tiles never cross a matrix boundary)
    int tid = (int)threadIdx.x;
    int wave = tid >> 6, lane = tid & 63;
    int g = lane >> 4, r4 = lane & 15;

#pragma unroll
    for (int j = 0; j < 16; ++j) {
        int s = tid + 256 * j;
        int local = s & 2047;
        int row = local >> 5;
        int col16 = (local & 31) ^ (row & 7);
        const unsigned short* src = (s < 2048)
            ? (seqb + (size_t)(m0 + row) * 256 + col16 * 8)
            : (Wt + (size_t)(c0 + row) * 256 + col16 * 8);
        __builtin_amdgcn_global_load_lds(
            (const __attribute__((address_space(1))) unsigned int*)src,
            (__attribute__((address_space(3))) unsigned int*)(&plds[s * 8]), 16, 0, 0);
    }
    __syncthreads();  // drains vmcnt(0): both tiles resident

    const unsigned short* ldsA = plds;
    const unsigned short* ldsB = plds + 16384;
    int rowA = wave * 16 + r4;
    int xA = r4 & 7;

    float4v acc[4];
#pragma unroll
    for (int ct = 0; ct < 4; ++ct) acc[ct] = (float4v){0.f, 0.f, 0.f, 0.f};

#pragma unroll
    for (int i = 0; i < 8; ++i) {
        int cp = ((4 * i + g) ^ xA) * 8;
        short8 a = *(const short8*)(ldsA + rowA * 256 + cp);
#pragma unroll
        for (int ct = 0; ct < 4; ++ct) {
            short8 b = *(const short8*)(ldsB + (ct * 16 + r4) * 256 + cp);
            acc[ct] = __builtin_amdgcn_mfma_f32_16x16x32_bf16(a, b, acc[ct], 0, 0, 0);
        }
    }

    const float SC = 0.17677669529663687f * 1.4426950408889634f;  // 1/sqrt(32)*log2(e)
    if (c0 < 512) {
        // ---- Q/K path: direct stores ----
#pragma unroll
        for (int ct = 0; ct < 4; ++ct) {
            int c = c0 + ct * 16 + r4;
            int mat = c >> 8;
            int cm = c & 255;
            int h = cm >> 5, e = cm & 31;
            float bias = ((mat == 0) ? bq : bk)[cm];
#pragma unroll
            for (int r = 0; r < 4; ++r) {
                int m = m0 + wave * 16 + 4 * g + r;
                int b = m >> 11, s = m & 2047;
                float val = acc[ct][r] + bias;
                if (mat == 0) Q[((b * NH + h) * NS + s) * NDH + e] = f2bf(val * SC);
                else          K[((b * NH + h) * NS + s) * NDH + e] = f2bf(val);
            }
        }
    } else {
        // ---- V path: LDS transpose, then 16B-contiguous stores ----
        int cmb = c0 & 255;                 // = c0 - 512
        unsigned short* T = plds;           // reuse (72-short padded rows)
        __syncthreads();                    // all MFMA reads of plds done
#pragma unroll
        for (int ct = 0; ct < 4; ++ct) {
            int j = ct * 16 + r4;           // local col (h,e index)
            float bias = bv[cmb + j];
#pragma unroll
            for (int r = 0; r < 4; ++r) {
                int i = wave * 16 + 4 * g + r;  // local m
                T[j * 72 + i] = f2bf(acc[ct][r] + bias);
            }
        }
        __syncthreads();
        int b = m0 >> 11, s0 = m0 & 2047;
#pragma unroll
        for (int kk = 0; kk < 2; ++kk) {
            int cid = tid + kk * 256;       // 512 chunks of 16B
            int j = cid >> 3, ch = cid & 7;
            int cm = cmb + j;
            int h = cm >> 5, e = cm & 31;
            short8 v = *(const short8*)(T + j * 72 + ch * 8);
            *(short8*)(Vt + ((size_t)(b * NH + h) * NDH + e) * NS + s0 + ch * 8) = v;
        }
    }
}

// ---------------- flash attention: split-K, wave-private pipelines (r14) ----------------
__global__ __launch_bounds__(256, 4) void attn_kernel(const unsigned short* __restrict__ Q,
                                                      const unsigned short* __restrict__ K,
                                                      const unsigned short* __restrict__ Vt,
                                                      float* __restrict__ out) {
    __shared__ __align__(16) char smem[37888];  // stage 32KB (union) | part 36864B | pll 1KB

    int bx = (int)blockIdx.x;
    int wid = (bx & 7) * 128 + (bx >> 3);  // XCD swizzle (1024 % 8 == 0)
    int bh = wid >> 5;
    int qt = wid & 31;
    int tid = (int)threadIdx.x;
    int wave = tid >> 6, lane = tid & 63;
    int r31 = lane & 31, hi2 = lane >> 5;
    int q0 = qt * 64;
    int kv0 = wave * KW;

    const unsigned short* Qb = Q + (size_t)bh * NS * NDH;
    const unsigned short* Kb = K + (size_t)bh * NS * NDH;
    const unsigned short* Vb = Vt + (size_t)bh * NDH * NS;

    auto mkK = [&](int slot) -> const unsigned short* {
        int row = slot >> 2;
        int srcC = (slot & 3) ^ ((row >> 1) & 3);
        int key = (row & ~12) | ((row & 4) << 1) | ((row & 8) >> 1);  // swap bits 2,3
        return Kb + (size_t)(kv0 + key) * NDH + srcC * 8;
    };
    auto mkV = [&](int sp) -> const unsigned short* {
        int row = sp >> 2;
        int srcC = (sp & 3) ^ ((row >> 1) & 3);
        return Vb + (size_t)row * NS + kv0 + srcC * 8;
    };
    const unsigned short* sp0 = mkK(lane);
    const unsigned short* sp1 = mkK(64 + lane);
    const unsigned short* sp2 = mkV(lane);
    const unsigned short* sp3 = mkV(64 + lane);

    char* bufA = smem + wave * 8192;
    char* bufB = bufA + 4096;

#define GLD(srcp, dstp)                                                        \
    __builtin_amdgcn_global_load_lds(                                          \
        (const __attribute__((address_space(1))) unsigned int*)(srcp),         \
        (__attribute__((address_space(3))) unsigned int*)(dstp), 16, 0, 0)

#define STAGE(bufp, t)                                                         \
    do {                                                                       \
        GLD(sp0 + (t) * 1024, (bufp) + lane * 16);                             \
        GLD(sp1 + (t) * 1024, (bufp) + 1024 + lane * 16);                      \
        GLD(sp2 + (t) * 32,   (bufp) + 2048 + lane * 16);                      \
        GLD(sp3 + (t) * 32,   (bufp) + 3072 + lane * 16);                      \
    } while (0)

    int rx = (r31 >> 1) & 3;
    int kOffA = r31 * 64 + ((hi2 ^ rx) << 4);
    int kOffB = r31 * 64 + (((2 + hi2) ^ rx) << 4);
    int vOffA = 2048 + r31 * 64 + ((hi2 ^ rx) << 4);
    int vOffB = 2048 + r31 * 64 + (((2 + hi2) ^ rx) << 4);

    const unsigned short* qrow0 = Qb + (q0 + r31) * NDH;
    const unsigned short* qrow1 = Qb + (q0 + 32 + r31) * NDH;
    short8 qa0 = *(const short8*)(qrow0 + 8 * hi2);
    short8 qb0 = *(const short8*)(qrow0 + 16 + 8 * hi2);
    short8 qa1 = *(const short8*)(qrow1 + 8 * hi2);
    short8 qb1 = *(const short8*)(qrow1 + 16 + 8 * hi2);
    asm volatile("s_waitcnt vmcnt(0)" ::: "memory");
    __builtin_amdgcn_sched_barrier(0);

    float16v acc0 = {0.f}, acc1 = {0.f};
    const float16v zero16 = {0.f};
    float l0 = 0.f, l1 = 0.f;

    auto process = [&](const char* buf) {
        short8 kfA = *(const short8*)(buf + kOffA);
        short8 kfB = *(const short8*)(buf + kOffB);
        short8 vfA = *(const short8*)(buf + vOffA);
        short8 vfB = *(const short8*)(buf + vOffB);
        {
            float16v s = __builtin_amdgcn_mfma_f32_32x32x16_bf16(kfA, qa0, zero16, 0, 0, 0);
            s = __builtin_amdgcn_mfma_f32_32x32x16_bf16(kfB, qb0, s, 0, 0, 0);
            float p[16];
#pragma unroll
            for (int r = 0; r < 16; ++r) p[r] = EXP2F(s[r]);
#pragma unroll
            for (int r = 0; r < 16; ++r) l0 += p[r];
            union { short8 v; unsigned int u[4]; } pb1, pb2;
#pragma unroll
            for (int w = 0; w < 4; ++w) {
                pb1.u[w] = pk2bf(p[2 * w], p[2 * w + 1]);
                pb2.u[w] = pk2bf(p[8 + 2 * w], p[9 + 2 * w]);
            }
            acc0 = __builtin_amdgcn_mfma_f32_32x32x16_bf16(vfA, pb1.v, acc0, 0, 0, 0);
            acc0 = __builtin_amdgcn_mfma_f32_32x32x16_bf16(vfB, pb2.v, acc0, 0, 0, 0);
        }
        {
            float16v s = __builtin_amdgcn_mfma_f32_32x32x16_bf16(kfA, qa1, zero16, 0, 0, 0);
            s = __builtin_amdgcn_mfma_f32_32x32x16_bf16(kfB, qb1, s, 0, 0, 0);
            float p[16];
#pragma unroll
            for (int r = 0; r < 16; ++r) p[r] = EXP2F(s[r]);
#pragma unroll
            for (int r = 0; r < 16; ++r) l1 += p[r];
            union { short8 v; unsigned int u[4]; } pb1, pb2;
#pragma unroll
            for (int w = 0; w < 4; ++w) {
                pb1.u[w] = pk2bf(p[2 * w], p[2 * w + 1]);
                pb2.u[w] = pk2bf(p[8 + 2 * w], p[9 + 2 * w]);
            }
            acc1 = __builtin_amdgcn_mfma_f32_32x32x16_bf16(vfA, pb1.v, acc1, 0, 0, 0);
            acc1 = __builtin_amdgcn_mfma_f32_32x32x16_bf16(vfB, pb2.v, acc1, 0, 0, 0);
        }
    };

    STAGE(bufA, 0);
    for (int t = 0; t < NTW; t += 2) {
        STAGE(bufB, t + 1);
        asm volatile("s_waitcnt vmcnt(4)" ::: "memory");
        __builtin_amdgcn_sched_barrier(0);
        __builtin_amdgcn_s_setprio(1);
        process(bufA);
        __builtin_amdgcn_s_setprio(0);

        if (t + 2 < NTW) {
            STAGE(bufA, t + 2);
            asm volatile("s_waitcnt vmcnt(4)" ::: "memory");
        } else {
            asm volatile("s_waitcnt vmcnt(0)" ::: "memory");
        }
        __builtin_amdgcn_sched_barrier(0);
        __builtin_amdgcn_s_setprio(1);
        process(bufB);
        __builtin_amdgcn_s_setprio(0);
    }

    // ---- split-K combine via LDS (exact: no-max softmax partials are additive) ----
    l0 += __shfl_xor(l0, 32);
    l1 += __shfl_xor(l1, 32);

    __syncthreads();
    float* part = (float*)smem;                 // [4][64][36] f32 (padded rows)
    float* pll = (float*)(smem + 36864);        // [4][64] f32
#pragma unroll
    for (int j = 0; j < 2; ++j) {
        int qlocal = 32 * j + r31;
        float* prow = part + (wave * 64 + qlocal) * 36 + 4 * hi2;
        const float16v& A = j ? acc1 : acc0;
#pragma unroll
        for (int i = 0; i < 4; ++i) {
            float4 v4 = {A[4 * i], A[4 * i + 1], A[4 * i + 2], A[4 * i + 3]};
            *(float4*)(prow + 8 * i) = v4;
        }
    }
    if (lane < 32) {
        pll[wave * 64 + r31] = l0;
        pll[wave * 64 + 32 + r31] = l1;
    }
    __syncthreads();

    {
        int q = tid >> 2, ch = tid & 3;
        float lsum = pll[q] + pll[64 + q] + pll[128 + q] + pll[192 + q];
        float inv = 1.0f / lsum;
        float4 s0 = {0.f, 0.f, 0.f, 0.f}, s1 = {0.f, 0.f, 0.f, 0.f};
#pragma unroll
        for (int w = 0; w < 4; ++w) {
            const float* prow = part + (w * 64 + q) * 36 + ch * 8;
            float4 a = *(const float4*)(prow);
            float4 b = *(const float4*)(prow + 4);
            s0.x += a.x; s0.y += a.y; s0.z += a.z; s0.w += a.w;
            s1.x += b.x; s1.y += b.y; s1.z += b.z; s1.w += b.w;
        }
        s0.x *= inv; s0.y *= inv; s0.z *= inv; s0.w *= inv;
        s1.x *= inv; s1.y *= inv; s1.z *= inv; s1.w *= inv;
        int b = bh >> 3, h = bh & 7;
        int srow = q0 + q;
        float* op = out + (size_t)(b * NS + srow) * ND + h * NDH + ch * 8;
        *(float4*)(op) = s0;
        *(float4*)(op + 4) = s1;
    }
#undef STAGE
#undef GLD
}

extern "C" void kernel_launch(void* const* d_in, const int* in_sizes, int n_in,
                              void* d_out, int out_size, void* d_ws, size_t ws_size,
                              hipStream_t stream) {
    const float* seq = (const float*)d_in[0];
    const float* Wq = (const float*)d_in[1];
    const float* Wk = (const float*)d_in[2];
    const float* Wv = (const float*)d_in[3];
    const float* bq = (const float*)d_in[4];
    const float* bk = (const float*)d_in[5];
    const float* bv = (const float*)d_in[6];
    float* out = (float*)d_out;

    // workspace layout (bf16 elements): seqb 2M | Wt 196608 | Q 2M | K 2M | Vt 2M  (~17.2 MB)
    unsigned short* seqb = (unsigned short*)d_ws;
    unsigned short* Wt = seqb + 2097152;
    unsigned short* Qw = Wt + 196608;
    unsigned short* Kw = Qw + 2097152;
    unsigned short* Vtw = Kw + 2097152;

    // ATTRIBUTION PROBE #2: prep and proj launched twice (idempotent).
    // dur - 53.8 = prep+proj cost.
    hipLaunchKernelGGL(prep, dim3(2816), dim3(256), 0, stream, seq, seqb, Wq, Wk, Wv, Wt);
    hipLaunchKernelGGL(prep, dim3(2816), dim3(256), 0, stream, seq, seqb, Wq, Wk, Wv, Wt);
    hipLaunchKernelGGL(proj, dim3(128, 12), dim3(256), 0, stream, seqb, Wt, bq, bk, bv, Qw, Kw, Vtw);
    hipLaunchKernelGGL(proj, dim3(128, 12), dim3(256), 0, stream, seqb, Wt, bq, bk, bv, Qw, Kw, Vtw);
    hipLaunchKernelGGL(attn_kernel, dim3(1024), dim3(256), 0, stream, Qw, Kw, Vtw, out);
}

// Round 19
// 53.761 us; speedup vs baseline: 1.5508x; 1.2570x over previous
//
#include <hip/hip_runtime.h>
#include <hip/hip_bf16.h>

// MSA: B=4, S=2048, D=256, H=8, DH=32
// q/k/v = seq @ W[h] + b[h]; out = softmax(q k^T / sqrt(32)) v, heads hstacked -> [B,S,D] f32
//
// proj: LDS-staged GEMM + V output transposed through LDS (16B-contiguous
// Vt stores). attn: split-K: 4 waves x 512-key quarters, wave-private LDS
// double buffers, no in-loop barriers; 32x32x16 MFMA; sigma-permuted K rows
// so QK acc regs ARE the PV B-frags; no-max softmax (exact split-K combine).
// NEW (r19): l accumulated via v_dot2_f32_bf16 on the packed P words
// (8 dot2/q-block replace 16 scalar adds -- attn is issue-bound, measured
// r17/r18 attribution: attn 29.6us, prep+proj 13.8us, fixed overhead ~10us).

#define NB 4
#define NS 2048
#define ND 256
#define NH 8
#define NDH 32
#define KW 512           // keys per wave (split-K quarter)
#define NTW (KW / 32)    // 16 sub-tiles of 32 keys per wave

typedef __attribute__((ext_vector_type(8))) short short8;
typedef __attribute__((ext_vector_type(4))) float float4v;
typedef __attribute__((ext_vector_type(16))) float float16v;

static __device__ __forceinline__ unsigned short f2bf(float f) {
    union { float f; unsigned int u; } v; v.f = f;
    unsigned int r = (v.u + 0x7FFFu + ((v.u >> 16) & 1u)) >> 16;
    return (unsigned short)r;
}

static __device__ __forceinline__ unsigned int pk2bf(float lo, float hi) {
    __hip_bfloat162 h = __float22bfloat162_rn(float2{lo, hi});  // x=lo -> low 16 bits
    union { __hip_bfloat162 h; unsigned int u; } c; c.h = h;
    return c.u;
}

// l += pb.lo + pb.hi  (bf16 pair dotted with (1.0,1.0)) -- one VOP3P op
static __device__ __forceinline__ float dot2l(unsigned int pbw, unsigned int onesv, float l) {
    float d;
    asm("v_dot2_f32_bf16 %0, %1, %2, %3" : "=v"(d) : "v"(pbw), "v"(onesv), "v"(l));
    return d;
}

#if defined(__has_builtin)
#if __has_builtin(__builtin_amdgcn_exp2f)
#define EXP2F(x) __builtin_amdgcn_exp2f(x)
#endif
#endif
#ifndef EXP2F
#define EXP2F(x) exp2f(x)
#endif

// ---------------- fused prep: seq f32->bf16 (blocks 0..2047), W transpose (2048..2815) ----------------
__global__ __launch_bounds__(256) void prep(const float* __restrict__ seq,
                                            unsigned short* __restrict__ seqb,
                                            const float* __restrict__ Wq,
                                            const float* __restrict__ Wk,
                                            const float* __restrict__ Wv,
                                            unsigned short* __restrict__ Wt) {
    int bx = (int)blockIdx.x;
    if (bx < 2048) {
        int i = (bx * 256 + (int)threadIdx.x) * 4;  // 2M elems / 4
        float4 v = *(const float4*)(seq + i);
        ushort4 o;
        o.x = f2bf(v.x); o.y = f2bf(v.y); o.z = f2bf(v.z); o.w = f2bf(v.w);
        *(ushort4*)(seqb + i) = o;
    } else {
        int idx = (bx - 2048) * 256 + (int)threadIdx.x;  // 768*256
        int c = idx >> 8, d = idx & 255;
        int mat = c >> 8;
        int cm = c & 255;
        int h = cm >> 5, e = cm & 31;
        const float* W = (mat == 0) ? Wq : (mat == 1) ? Wk : Wv;
        Wt[c * 256 + d] = f2bf(W[(h * 256 + d) * 32 + e]);
    }
}

// ---------------- projection GEMM: M=8192, N=768, K=256, LDS-staged ----------------
__global__ __launch_bounds__(256, 2) void proj(const unsigned short* __restrict__ seqb,
                                               const unsigned short* __restrict__ Wt,
                                               const float* __restrict__ bq,
                                               const float* __restrict__ bk,
                                               const float* __restrict__ bv,
                                               unsigned short* __restrict__ Q,
                                               unsigned short* __restrict__ K,
                                               unsigned short* __restrict__ Vt) {
    __shared__ __align__(16) unsigned short plds[32768];  // A [0,16384), B [16384,32768)

    int m0 = blockIdx.x * 64;        // 128 m-blocks
    int c0 = blockIdx.y * 64;        // 12 c-blocks (64-col tiles never cross a matrix boundary)
    int tid = (int)threadIdx.x;
    int wave = tid >> 6, lane = tid & 63;
    int g = lane >> 4, r4 = lane & 15;

#pragma unroll
    for (int j = 0; j < 16; ++j) {
        int s = tid + 256 * j;
        int local = s & 2047;
        int row = local >> 5;
        int col16 = (local & 31) ^ (row & 7);
        const unsigned short* src = (s < 2048)
            ? (seqb + (size_t)(m0 + row) * 256 + col16 * 8)
            : (Wt + (size_t)(c0 + row) * 256 + col16 * 8);
        __builtin_amdgcn_global_load_lds(
            (const __attribute__((address_space(1))) unsigned int*)src,
            (__attribute__((address_space(3))) unsigned int*)(&plds[s * 8]), 16, 0, 0);
    }
    __syncthreads();  // drains vmcnt(0): both tiles resident

    const unsigned short* ldsA = plds;
    const unsigned short* ldsB = plds + 16384;
    int rowA = wave * 16 + r4;
    int xA = r4 & 7;

    float4v acc[4];
#pragma unroll
    for (int ct = 0; ct < 4; ++ct) acc[ct] = (float4v){0.f, 0.f, 0.f, 0.f};

#pragma unroll
    for (int i = 0; i < 8; ++i) {
        int cp = ((4 * i + g) ^ xA) * 8;
        short8 a = *(const short8*)(ldsA + rowA * 256 + cp);
#pragma unroll
        for (int ct = 0; ct < 4; ++ct) {
            short8 b = *(const short8*)(ldsB + (ct * 16 + r4) * 256 + cp);
            acc[ct] = __builtin_amdgcn_mfma_f32_16x16x32_bf16(a, b, acc[ct], 0, 0, 0);
        }
    }

    const float SC = 0.17677669529663687f * 1.4426950408889634f;  // 1/sqrt(32)*log2(e)
    if (c0 < 512) {
        // ---- Q/K path: direct stores ----
#pragma unroll
        for (int ct = 0; ct < 4; ++ct) {
            int c = c0 + ct * 16 + r4;
            int mat = c >> 8;
            int cm = c & 255;
            int h = cm >> 5, e = cm & 31;
            float bias = ((mat == 0) ? bq : bk)[cm];
#pragma unroll
            for (int r = 0; r < 4; ++r) {
                int m = m0 + wave * 16 + 4 * g + r;
                int b = m >> 11, s = m & 2047;
                float val = acc[ct][r] + bias;
                if (mat == 0) Q[((b * NH + h) * NS + s) * NDH + e] = f2bf(val * SC);
                else          K[((b * NH + h) * NS + s) * NDH + e] = f2bf(val);
            }
        }
    } else {
        // ---- V path: LDS transpose, then 16B-contiguous stores ----
        int cmb = c0 & 255;                 // = c0 - 512
        unsigned short* T = plds;           // reuse (72-short padded rows)
        __syncthreads();                    // all MFMA reads of plds done
#pragma unroll
        for (int ct = 0; ct < 4; ++ct) {
            int j = ct * 16 + r4;           // local col (h,e index)
            float bias = bv[cmb + j];
#pragma unroll
            for (int r = 0; r < 4; ++r) {
                int i = wave * 16 + 4 * g + r;  // local m
                T[j * 72 + i] = f2bf(acc[ct][r] + bias);
            }
        }
        __syncthreads();
        int b = m0 >> 11, s0 = m0 & 2047;
#pragma unroll
        for (int kk = 0; kk < 2; ++kk) {
            int cid = tid + kk * 256;       // 512 chunks of 16B
            int j = cid >> 3, ch = cid & 7;
            int cm = cmb + j;
            int h = cm >> 5, e = cm & 31;
            short8 v = *(const short8*)(T + j * 72 + ch * 8);
            *(short8*)(Vt + ((size_t)(b * NH + h) * NDH + e) * NS + s0 + ch * 8) = v;
        }
    }
}

// ---------------- flash attention: split-K, wave-private pipelines ----------------
__global__ __launch_bounds__(256, 4) void attn_kernel(const unsigned short* __restrict__ Q,
                                                      const unsigned short* __restrict__ K,
                                                      const unsigned short* __restrict__ Vt,
                                                      float* __restrict__ out) {
    __shared__ __align__(16) char smem[37888];  // stage 32KB (union) | part 36864B | pll 1KB

    int bx = (int)blockIdx.x;
    int wid = (bx & 7) * 128 + (bx >> 3);  // XCD swizzle (1024 % 8 == 0)
    int bh = wid >> 5;
    int qt = wid & 31;
    int tid = (int)threadIdx.x;
    int wave = tid >> 6, lane = tid & 63;
    int r31 = lane & 31, hi2 = lane >> 5;
    int q0 = qt * 64;
    int kv0 = wave * KW;

    const unsigned short* Qb = Q + (size_t)bh * NS * NDH;
    const unsigned short* Kb = K + (size_t)bh * NS * NDH;
    const unsigned short* Vb = Vt + (size_t)bh * NDH * NS;

    auto mkK = [&](int slot) -> const unsigned short* {
        int row = slot >> 2;
        int srcC = (slot & 3) ^ ((row >> 1) & 3);
        int key = (row & ~12) | ((row & 4) << 1) | ((row & 8) >> 1);  // swap bits 2,3
        return Kb + (size_t)(kv0 + key) * NDH + srcC * 8;
    };
    auto mkV = [&](int sp) -> const unsigned short* {
        int row = sp >> 2;
        int srcC = (sp & 3) ^ ((row >> 1) & 3);
        return Vb + (size_t)row * NS + kv0 + srcC * 8;
    };
    const unsigned short* sp0 = mkK(lane);
    const unsigned short* sp1 = mkK(64 + lane);
    const unsigned short* sp2 = mkV(lane);
    const unsigned short* sp3 = mkV(64 + lane);

    char* bufA = smem + wave * 8192;
    char* bufB = bufA + 4096;

#define GLD(srcp, dstp)                                                        \
    __builtin_amdgcn_global_load_lds(                                          \
        (const __attribute__((address_space(1))) unsigned int*)(srcp),         \
        (__attribute__((address_space(3))) unsigned int*)(dstp), 16, 0, 0)

#define STAGE(bufp, t)                                                         \
    do {                                                                       \
        GLD(sp0 + (t) * 1024, (bufp) + lane * 16);                             \
        GLD(sp1 + (t) * 1024, (bufp) + 1024 + lane * 16);                      \
        GLD(sp2 + (t) * 32,   (bufp) + 2048 + lane * 16);                      \
        GLD(sp3 + (t) * 32,   (bufp) + 3072 + lane * 16);                      \
    } while (0)

    int rx = (r31 >> 1) & 3;
    int kOffA = r31 * 64 + ((hi2 ^ rx) << 4);
    int kOffB = r31 * 64 + (((2 + hi2) ^ rx) << 4);
    int vOffA = 2048 + r31 * 64 + ((hi2 ^ rx) << 4);
    int vOffB = 2048 + r31 * 64 + (((2 + hi2) ^ rx) << 4);

    const unsigned short* qrow0 = Qb + (q0 + r31) * NDH;
    const unsigned short* qrow1 = Qb + (q0 + 32 + r31) * NDH;
    short8 qa0 = *(const short8*)(qrow0 + 8 * hi2);
    short8 qb0 = *(const short8*)(qrow0 + 16 + 8 * hi2);
    short8 qa1 = *(const short8*)(qrow1 + 8 * hi2);
    short8 qb1 = *(const short8*)(qrow1 + 16 + 8 * hi2);
    asm volatile("s_waitcnt vmcnt(0)" ::: "memory");
    __builtin_amdgcn_sched_barrier(0);

    float16v acc0 = {0.f}, acc1 = {0.f};
    const float16v zero16 = {0.f};
    float l0 = 0.f, l1 = 0.f;
    const unsigned int onesv = 0x3F803F80u;  // bf16 (1.0, 1.0)

    auto process = [&](const char* buf) {
        short8 kfA = *(const short8*)(buf + kOffA);
        short8 kfB = *(const short8*)(buf + kOffB);
        short8 vfA = *(const short8*)(buf + vOffA);
        short8 vfB = *(const short8*)(buf + vOffB);
        {
            float16v s = __builtin_amdgcn_mfma_f32_32x32x16_bf16(kfA, qa0, zero16, 0, 0, 0);
            s = __builtin_amdgcn_mfma_f32_32x32x16_bf16(kfB, qb0, s, 0, 0, 0);
            float p[16];
#pragma unroll
            for (int r = 0; r < 16; ++r) p[r] = EXP2F(s[r]);
            union { short8 v; unsigned int u[4]; } pb1, pb2;
#pragma unroll
            for (int w = 0; w < 4; ++w) {
                pb1.u[w] = pk2bf(p[2 * w], p[2 * w + 1]);
                pb2.u[w] = pk2bf(p[8 + 2 * w], p[9 + 2 * w]);
            }
#pragma unroll
            for (int w = 0; w < 4; ++w) {
                l0 = dot2l(pb1.u[w], onesv, l0);
                l0 = dot2l(pb2.u[w], onesv, l0);
            }
            acc0 = __builtin_amdgcn_mfma_f32_32x32x16_bf16(vfA, pb1.v, acc0, 0, 0, 0);
            acc0 = __builtin_amdgcn_mfma_f32_32x32x16_bf16(vfB, pb2.v, acc0, 0, 0, 0);
        }
        {
            float16v s = __builtin_amdgcn_mfma_f32_32x32x16_bf16(kfA, qa1, zero16, 0, 0, 0);
            s = __builtin_amdgcn_mfma_f32_32x32x16_bf16(kfB, qb1, s, 0, 0, 0);
            float p[16];
#pragma unroll
            for (int r = 0; r < 16; ++r) p[r] = EXP2F(s[r]);
            union { short8 v; unsigned int u[4]; } pb1, pb2;
#pragma unroll
            for (int w = 0; w < 4; ++w) {
                pb1.u[w] = pk2bf(p[2 * w], p[2 * w + 1]);
                pb2.u[w] = pk2bf(p[8 + 2 * w], p[9 + 2 * w]);
            }
#pragma unroll
            for (int w = 0; w < 4; ++w) {
                l1 = dot2l(pb1.u[w], onesv, l1);
                l1 = dot2l(pb2.u[w], onesv, l1);
            }
            acc1 = __builtin_amdgcn_mfma_f32_32x32x16_bf16(vfA, pb1.v, acc1, 0, 0, 0);
            acc1 = __builtin_amdgcn_mfma_f32_32x32x16_bf16(vfB, pb2.v, acc1, 0, 0, 0);
        }
    };

    STAGE(bufA, 0);
    for (int t = 0; t < NTW; t += 2) {
        STAGE(bufB, t + 1);
        asm volatile("s_waitcnt vmcnt(4)" ::: "memory");
        __builtin_amdgcn_sched_barrier(0);
        __builtin_amdgcn_s_setprio(1);
        process(bufA);
        __builtin_amdgcn_s_setprio(0);

        if (t + 2 < NTW) {
            STAGE(bufA, t + 2);
            asm volatile("s_waitcnt vmcnt(4)" ::: "memory");
        } else {
            asm volatile("s_waitcnt vmcnt(0)" ::: "memory");
        }
        __builtin_amdgcn_sched_barrier(0);
        __builtin_amdgcn_s_setprio(1);
        process(bufB);
        __builtin_amdgcn_s_setprio(0);
    }

    // ---- split-K combine via LDS (exact: no-max softmax partials are additive) ----
    l0 += __shfl_xor(l0, 32);
    l1 += __shfl_xor(l1, 32);

    __syncthreads();
    float* part = (float*)smem;                 // [4][64][36] f32 (padded rows)
    float* pll = (float*)(smem + 36864);        // [4][64] f32
#pragma unroll
    for (int j = 0; j < 2; ++j) {
        int qlocal = 32 * j + r31;
        float* prow = part + (wave * 64 + qlocal) * 36 + 4 * hi2;
        const float16v& A = j ? acc1 : acc0;
#pragma unroll
        for (int i = 0; i < 4; ++i) {
            float4 v4 = {A[4 * i], A[4 * i + 1], A[4 * i + 2], A[4 * i + 3]};
            *(float4*)(prow + 8 * i) = v4;
        }
    }
    if (lane < 32) {
        pll[wave * 64 + r31] = l0;
        pll[wave * 64 + 32 + r31] = l1;
    }
    __syncthreads();

    {
        int q = tid >> 2, ch = tid & 3;
        float lsum = pll[q] + pll[64 + q] + pll[128 + q] + pll[192 + q];
        float inv = 1.0f / lsum;
        float4 s0 = {0.f, 0.f, 0.f, 0.f}, s1 = {0.f, 0.f, 0.f, 0.f};
#pragma unroll
        for (int w = 0; w < 4; ++w) {
            const float* prow = part + (w * 64 + q) * 36 + ch * 8;
            float4 a = *(const float4*)(prow);
            float4 b = *(const float4*)(prow + 4);
            s0.x += a.x; s0.y += a.y; s0.z += a.z; s0.w += a.w;
            s1.x += b.x; s1.y += b.y; s1.z += b.z; s1.w += b.w;
        }
        s0.x *= inv; s0.y *= inv; s0.z *= inv; s0.w *= inv;
        s1.x *= inv; s1.y *= inv; s1.z *= inv; s1.w *= inv;
        int b = bh >> 3, h = bh & 7;
        int srow = q0 + q;
        float* op = out + (size_t)(b * NS + srow) * ND + h * NDH + ch * 8;
        *(float4*)(op) = s0;
        *(float4*)(op + 4) = s1;
    }
#undef STAGE
#undef GLD
}

extern "C" void kernel_launch(void* const* d_in, const int* in_sizes, int n_in,
                              void* d_out, int out_size, void* d_ws, size_t ws_size,
                              hipStream_t stream) {
    const float* seq = (const float*)d_in[0];
    const float* Wq = (const float*)d_in[1];
    const float* Wk = (const float*)d_in[2];
    const float* Wv = (const float*)d_in[3];
    const float* bq = (const float*)d_in[4];
    const float* bk = (const float*)d_in[5];
    const float* bv = (const float*)d_in[6];
    float* out = (float*)d_out;

    // workspace layout (bf16 elements): seqb 2M | Wt 196608 | Q 2M | K 2M | Vt 2M  (~17.2 MB)
    unsigned short* seqb = (unsigned short*)d_ws;
    unsigned short* Wt = seqb + 2097152;
    unsigned short* Qw = Wt + 196608;
    unsigned short* Kw = Qw + 2097152;
    unsigned short* Vtw = Kw + 2097152;

    hipLaunchKernelGGL(prep, dim3(2816), dim3(256), 0, stream, seq, seqb, Wq, Wk, Wv, Wt);
    hipLaunchKernelGGL(proj, dim3(128, 12), dim3(256), 0, stream, seqb, Wt, bq, bk, bv, Qw, Kw, Vtw);
    hipLaunchKernelGGL(attn_kernel, dim3(1024), dim3(256), 0, stream, Qw, Kw, Vtw, out);
}